// Round 1
// baseline (492.076 us; speedup 1.0000x reference)
//
#include <hip/hip_runtime.h>
#include <stdint.h>

// ---- problem constants ----
#define IN_F   4096
#define OUT_F  4096
#define M_ROWS 8192          // 4 * 2048
#define RANK   8

typedef int v4i __attribute__((ext_vector_type(4)));

// q = clip(rint(v / s), -8, 7)   (round-half-even matches jnp.round)
__device__ __forceinline__ int qone(float v, float s) {
    float q = rintf(v / s);
    q = fminf(fmaxf(q, -8.0f), 7.0f);
    return (int)q;
}

__device__ __forceinline__ uint32_t qpack4(float a, float b, float c, float d, float s) {
    uint32_t r =  (uint32_t)(qone(a, s) & 0xFF)
               | ((uint32_t)(qone(b, s) & 0xFF) << 8)
               | ((uint32_t)(qone(c, s) & 0xFF) << 16)
               | ((uint32_t)(qone(d, s) & 0xFF) << 24);
    return r;
}

// ---- kernel 1: merged-weight quant  (W + lora_B @ lora_A, per-row scale) ----
__global__ void quant_w_k(const float* __restrict__ W,
                          const float* __restrict__ lA,
                          const float* __restrict__ lB,
                          const float* __restrict__ sw,
                          uint32_t* __restrict__ qw) {
    int i = blockIdx.x * blockDim.x + threadIdx.x;   // over OUT_F*IN_F/4 = 4194304
    int o = i >> 10;                                  // IN_F/4 = 1024
    int c = i & 1023;
    float4 w = reinterpret_cast<const float4*>(W)[i];
    const float* bo = lB + o * RANK;
#pragma unroll
    for (int r = 0; r < RANK; ++r) {
        float br = bo[r];
        float4 a = reinterpret_cast<const float4*>(lA)[r * 1024 + c];
        w.x = fmaf(br, a.x, w.x);
        w.y = fmaf(br, a.y, w.y);
        w.z = fmaf(br, a.z, w.z);
        w.w = fmaf(br, a.w, w.w);
    }
    qw[i] = qpack4(w.x, w.y, w.z, w.w, sw[o]);
}

// ---- kernel 2: activation quant (scalar temporal scale) ----
__global__ void quant_x_k(const float* __restrict__ x,
                          const float* __restrict__ ts,
                          const int* __restrict__ step,
                          uint32_t* __restrict__ qx) {
    const float s = ts[step[0]];
    int i = blockIdx.x * blockDim.x + threadIdx.x;   // over M_ROWS*IN_F/4 = 8388608
    float4 v = reinterpret_cast<const float4*>(x)[i];
    qx[i] = qpack4(v.x, v.y, v.z, v.w, s);
}

// ---- kernel 3: int8 MFMA GEMM  out = (qx @ qw^T) * (s_x*s_w[o]) + bias ----
#define BM 128
#define BN 128
#define BK 64
#define LTILE (BM * BK)   // 8192 bytes per int8 tile

__device__ __forceinline__ void gload16(const void* g, void* l) {
    __builtin_amdgcn_global_load_lds(
        (const __attribute__((address_space(1))) void*)g,
        (__attribute__((address_space(3))) void*)l,
        16, 0, 0);
}

__global__ __launch_bounds__(256) void gemm_i8_k(
    const char* __restrict__ qx, const char* __restrict__ qw,
    const float* __restrict__ sw, const float* __restrict__ ts,
    const int* __restrict__ step, const float* __restrict__ bias,
    float* __restrict__ out) {

    __shared__ __attribute__((aligned(16))) char lsA[2][LTILE];
    __shared__ __attribute__((aligned(16))) char lsB[2][LTILE];

    const int t    = threadIdx.x;
    const int lane = t & 63;
    const int wave = t >> 6;
    const int wm   = wave >> 1;      // 2x2 waves, each 64x64 output
    const int wn   = wave & 1;

    // XCD-aware swizzle (2048 blocks, 2048 % 8 == 0 -> bijective simple form)
    int bid = blockIdx.x;
    int swz = (bid & 7) * 256 + (bid >> 3);
    const int tn = swz & 31;         // 4096/128 = 32 n-tiles
    const int tm = swz >> 5;         // 8192/128 = 64 m-tiles

    // staging: per round p (0/1), thread t covers LDS bytes [p*4096 + t*16, +16)
    // linear layout: row = p*64 + t/4, physical 16B-slot = t%4.
    // LDS dest stays LINEAR (global_load_lds requirement); the 4-chunk XOR
    // swizzle f(row) is applied on the GLOBAL source and again on the read.
    const int srow  = t >> 2;
    const int sslot = t & 3;

    auto stage = [&](int buf, int kt) {
        const size_t k0 = (size_t)kt * BK;
#pragma unroll
        for (int p = 0; p < 2; ++p) {
            int row = p * 64 + srow;
            int f   = (row ^ (row >> 2)) & 3;
            int cg  = sslot ^ f;
            gload16(qx + (size_t)(tm * BM + row) * IN_F + k0 + cg * 16,
                    &lsA[buf][p * 4096 + t * 16]);
            gload16(qw + (size_t)(tn * BN + row) * IN_F + k0 + cg * 16,
                    &lsB[buf][p * 4096 + t * 16]);
        }
    };

    auto rdA = [&](int buf, int mi) -> v4i {
        int row = wm * 64 + mi * 16 + (lane & 15);
        int kc  = lane >> 4;
        int f   = (row ^ (row >> 2)) & 3;
        return *(const v4i*)&lsA[buf][row * 64 + ((kc ^ f) << 4)];
    };
    auto rdB = [&](int buf, int ni) -> v4i {
        int row = wn * 64 + ni * 16 + (lane & 15);
        int kc  = lane >> 4;
        int f   = (row ^ (row >> 2)) & 3;
        return *(const v4i*)&lsB[buf][row * 64 + ((kc ^ f) << 4)];
    };

    v4i acc[4][4] = {};

    stage(0, 0);
    __syncthreads();

    int cur = 0;
    const int NT = IN_F / BK;        // 64
    for (int kt = 0; kt < NT; ++kt) {
        if (kt + 1 < NT) stage(cur ^ 1, kt + 1);

        v4i a[4], b[4];
#pragma unroll
        for (int mi = 0; mi < 4; ++mi) a[mi] = rdA(cur, mi);
#pragma unroll
        for (int ni = 0; ni < 4; ++ni) b[ni] = rdB(cur, ni);

#pragma unroll
        for (int mi = 0; mi < 4; ++mi)
#pragma unroll
            for (int ni = 0; ni < 4; ++ni)
                acc[mi][ni] = __builtin_amdgcn_mfma_i32_16x16x64_i8(
                    a[mi], b[ni], acc[mi][ni], 0, 0, 0);

        __syncthreads();             // drains vmcnt: staged buf ready, reads done
        cur ^= 1;
    }

    // epilogue: D layout col=lane&15 (N), row=(lane>>4)*4+reg (M)  [m89/m101]
    const float s_x = ts[step[0]];
#pragma unroll
    for (int ni = 0; ni < 4; ++ni) {
        int col  = tn * BN + wn * 64 + ni * 16 + (lane & 15);
        float sc = s_x * sw[col];
        float bv = bias[col];
#pragma unroll
        for (int mi = 0; mi < 4; ++mi) {
            int row0 = tm * BM + wm * 64 + mi * 16 + (lane >> 4) * 4;
#pragma unroll
            for (int r = 0; r < 4; ++r) {
                out[(size_t)(row0 + r) * OUT_F + col] =
                    (float)acc[mi][ni][r] * sc + bv;
            }
        }
    }
}

extern "C" void kernel_launch(void* const* d_in, const int* in_sizes, int n_in,
                              void* d_out, int out_size, void* d_ws, size_t ws_size,
                              hipStream_t stream) {
    const float* x    = (const float*)d_in[0];
    const float* W    = (const float*)d_in[1];
    const float* lA   = (const float*)d_in[2];
    const float* lB   = (const float*)d_in[3];
    const float* sw   = (const float*)d_in[4];
    const float* ts   = (const float*)d_in[5];
    const float* bias = (const float*)d_in[6];
    const int*   step = (const int*)d_in[7];
    float* out = (float*)d_out;

    char* qw = (char*)d_ws;                                   // 16 MiB
    char* qx = (char*)d_ws + (size_t)OUT_F * IN_F;            // 32 MiB

    quant_w_k<<<(OUT_F * IN_F / 4) / 256, 256, 0, stream>>>(W, lA, lB, sw, (uint32_t*)qw);
    quant_x_k<<<(M_ROWS * IN_F / 4) / 256, 256, 0, stream>>>(x, ts, step, (uint32_t*)qx);

    gemm_i8_k<<<(M_ROWS / BM) * (OUT_F / BN), 256, 0, stream>>>(
        (const char*)qx, (const char*)qw, sw, ts, step, bias, out);
}

// Round 2
// 425.483 us; speedup vs baseline: 1.1565x; 1.1565x over previous
//
#include <hip/hip_runtime.h>
#include <stdint.h>

#define IN_F   4096
#define OUT_F  4096
#define M_ROWS 8192
#define RANK   8

typedef int v4i __attribute__((ext_vector_type(4)));

__device__ __forceinline__ int qclamp(float v, float inv) {
    float q = rintf(v * inv);                 // v_rndne, round-half-even = jnp.round
    q = fminf(fmaxf(q, -8.0f), 7.0f);
    return (int)q;
}

__device__ __forceinline__ uint32_t qpack4(float4 v, float inv) {
    uint32_t r =  (uint32_t)(qclamp(v.x, inv) & 0xFF)
               | ((uint32_t)(qclamp(v.y, inv) & 0xFF) << 8)
               | ((uint32_t)(qclamp(v.z, inv) & 0xFF) << 16)
               | ((uint32_t)(qclamp(v.w, inv) & 0xFF) << 24);
    return r;
}

// ---- kernel 1: merged-weight quant. One block per output row o. ----
__global__ __launch_bounds__(256) void quant_w_k(
    const float* __restrict__ W, const float* __restrict__ lA,
    const float* __restrict__ lB, const float* __restrict__ sw,
    uint32_t* __restrict__ qw) {
    const int t = threadIdx.x;
    const int o = blockIdx.x;
    const float inv = 1.0f / sw[o];           // single division per thread
    float br[RANK];
#pragma unroll
    for (int r = 0; r < RANK; ++r) br[r] = lB[o * RANK + r];
    const float4* Wo = (const float4*)(W + (size_t)o * IN_F);
    const float4* A4 = (const float4*)lA;
#pragma unroll
    for (int k = 0; k < 4; ++k) {
        int i = k * 256 + t;                  // 1024 float4 per row
        float4 w = Wo[i];
#pragma unroll
        for (int r = 0; r < RANK; ++r) {
            float4 a = A4[r * 1024 + i];
            w.x = fmaf(br[r], a.x, w.x);
            w.y = fmaf(br[r], a.y, w.y);
            w.z = fmaf(br[r], a.z, w.z);
            w.w = fmaf(br[r], a.w, w.w);
        }
        qw[(size_t)o * 1024 + i] = qpack4(w, inv);
    }
}

// ---- kernel 2: activation quant ----
__global__ __launch_bounds__(256) void quant_x_k(
    const float* __restrict__ x, const float* __restrict__ ts,
    const int* __restrict__ step, uint32_t* __restrict__ qx) {
    const float inv = 1.0f / ts[step[0]];
    const int t = threadIdx.x;
    const size_t base = (size_t)blockIdx.x * 1024;
#pragma unroll
    for (int k = 0; k < 4; ++k) {
        size_t i = base + k * 256 + t;        // per-instr lane-contiguous
        float4 v = ((const float4*)x)[i];
        qx[i] = qpack4(v, inv);
    }
}

// ---- kernel 3: int8 MFMA GEMM, 256x256 tile, counted-vmcnt pipeline ----
#define BKB 64                    // K bytes per tile (= one K=64 i8 MFMA slice)
#define NTK (IN_F / BKB)          // 64 K-tiles
#define TILEB (256 * BKB)         // 16 KiB per matrix per buffer

__device__ __forceinline__ void gload16(const void* g, void* l) {
    __builtin_amdgcn_global_load_lds(
        (const __attribute__((address_space(1))) void*)g,
        (__attribute__((address_space(3))) void*)l,
        16, 0, 0);
}

__global__ __launch_bounds__(512, 2) void gemm_i8_k(
    const char* __restrict__ qx, const char* __restrict__ qw,
    const float* __restrict__ sw, const float* __restrict__ ts,
    const int* __restrict__ step, const float* __restrict__ bias,
    float* __restrict__ out) {

    __shared__ __attribute__((aligned(16))) char lsA[4][TILEB];  // 64 KiB
    __shared__ __attribute__((aligned(16))) char lsB[4][TILEB];  // 64 KiB

    const int t    = threadIdx.x;
    const int lane = t & 63;
    const int wave = t >> 6;          // 8 waves: 2M x 4N
    const int wm   = wave >> 2;       // 0..1 -> rows wm*128
    const int wn   = wave & 3;        // 0..3 -> cols wn*64

    // XCD swizzle: 512 blocks, 512 % 8 == 0 -> simple form bijective
    int bid = blockIdx.x;
    int swz = (bid & 7) * 64 + (bid >> 3);
    const int tn = swz & 15;          // 16 n-tiles
    const int tm = swz >> 4;          // 32 m-tiles

    const char* gA = qx + (size_t)tm * 256 * IN_F;
    const char* gB = qw + (size_t)tn * 256 * IN_F;

    // staging: issue j in {0,1}; i = j*512+t; row=i>>2, chunk=i&3 (linear LDS
    // dest per global_load_lds; XOR swizzle applied on the GLOBAL source)
    auto stage_j = [&](int bb, int T, int j) {
        int i   = j * 512 + t;
        int row = i >> 2;
        int cg  = (i & 3) ^ ((row >> 1) & 3);
        size_t goff = (size_t)row * IN_F + T * BKB + cg * 16;
        gload16(gA + goff, &lsA[bb][i * 16]);
        gload16(gB + goff, &lsB[bb][i * 16]);
    };
    // fragment reads: 16 lanes = 16 rows at chunk kc=lane>>4; swizzled -> 2-way banks
    auto rdA = [&](int bb, int mi) -> v4i {
        int r  = wm * 128 + mi * 16 + (lane & 15);
        int pc = (lane >> 4) ^ ((r >> 1) & 3);
        return *(const v4i*)&lsA[bb][r * BKB + pc * 16];
    };
    auto rdB = [&](int bb, int ni) -> v4i {
        int r  = wn * 64 + ni * 16 + (lane & 15);
        int pc = (lane >> 4) ^ ((r >> 1) & 3);
        return *(const v4i*)&lsB[bb][r * BKB + pc * 16];
    };

    v4i acc[8][4] = {};

    // prologue: stage tiles 0,1,2 (4 gloads each)
#pragma unroll
    for (int T0 = 0; T0 < 3; ++T0) { stage_j(T0, T0, 0); stage_j(T0, T0, 1); }

    for (int T = 0; T < NTK; ++T) {
        const int bb = T & 3;
        // counted wait: tiles T+1,T+2 (8 loads) may stay in flight; drain at tail
        if (T < NTK - 2)       asm volatile("s_waitcnt vmcnt(8)" ::: "memory");
        else if (T == NTK - 2) asm volatile("s_waitcnt vmcnt(4)" ::: "memory");
        else                   asm volatile("s_waitcnt vmcnt(0)" ::: "memory");
        __builtin_amdgcn_s_barrier();   // all waves' tile-T loads landed; reads of
                                        // tile T-1 are in regs -> T+3 staging safe

        // phase A: frags m0-3 x n0-3
        v4i av[4], bv[4];
#pragma unroll
        for (int mi = 0; mi < 4; ++mi) av[mi] = rdA(bb, mi);
#pragma unroll
        for (int ni = 0; ni < 4; ++ni) bv[ni] = rdB(bb, ni);
        if (T + 3 < NTK) stage_j((T + 3) & 3, T + 3, 0);
        __builtin_amdgcn_s_setprio(1);
#pragma unroll
        for (int mi = 0; mi < 4; ++mi)
#pragma unroll
            for (int ni = 0; ni < 4; ++ni)
                acc[mi][ni] = __builtin_amdgcn_mfma_i32_16x16x64_i8(
                    av[mi], bv[ni], acc[mi][ni], 0, 0, 0);
        __builtin_amdgcn_s_setprio(0);

        // phase B: frags m4-7 x n0-3 (B reused from regs)
        v4i aw[4];
#pragma unroll
        for (int mi = 0; mi < 4; ++mi) aw[mi] = rdA(bb, mi + 4);
        if (T + 3 < NTK) stage_j((T + 3) & 3, T + 3, 1);
        __builtin_amdgcn_s_setprio(1);
#pragma unroll
        for (int mi = 0; mi < 4; ++mi)
#pragma unroll
            for (int ni = 0; ni < 4; ++ni)
                acc[mi + 4][ni] = __builtin_amdgcn_mfma_i32_16x16x64_i8(
                    aw[mi], bv[ni], acc[mi + 4][ni], 0, 0, 0);
        __builtin_amdgcn_s_setprio(0);
    }

    // epilogue: D layout col=lane&15, row=(lane>>4)*4+reg  [m89/m101]
    const float s_x = ts[step[0]];
#pragma unroll
    for (int ni = 0; ni < 4; ++ni) {
        int col  = tn * 256 + wn * 64 + ni * 16 + (lane & 15);
        float sc = s_x * sw[col];
        float bv = bias[col];
#pragma unroll
        for (int mi = 0; mi < 8; ++mi) {
            int row0 = tm * 256 + wm * 128 + mi * 16 + (lane >> 4) * 4;
#pragma unroll
            for (int r = 0; r < 4; ++r) {
                out[(size_t)(row0 + r) * OUT_F + col] =
                    (float)acc[mi][ni][r] * sc + bv;
            }
        }
    }
}

extern "C" void kernel_launch(void* const* d_in, const int* in_sizes, int n_in,
                              void* d_out, int out_size, void* d_ws, size_t ws_size,
                              hipStream_t stream) {
    const float* x    = (const float*)d_in[0];
    const float* W    = (const float*)d_in[1];
    const float* lA   = (const float*)d_in[2];
    const float* lB   = (const float*)d_in[3];
    const float* sw   = (const float*)d_in[4];
    const float* ts   = (const float*)d_in[5];
    const float* bias = (const float*)d_in[6];
    const int*   step = (const int*)d_in[7];
    float* out = (float*)d_out;

    char* qw = (char*)d_ws;                                   // 16 MiB
    char* qx = (char*)d_ws + (size_t)OUT_F * IN_F;            // 32 MiB

    quant_w_k<<<OUT_F, 256, 0, stream>>>(W, lA, lB, sw, (uint32_t*)qw);
    quant_x_k<<<M_ROWS * IN_F / 4096, 256, 0, stream>>>(x, ts, step, (uint32_t*)qx);

    gemm_i8_k<<<(M_ROWS / 256) * (OUT_F / 256), 512, 0, stream>>>(
        (const char*)qx, (const char*)qw, sw, ts, step, bias, out);
}